// Round 7
// baseline (187.186 us; speedup 1.0000x reference)
//
#include <hip/hip_runtime.h>
#include <stdint.h>

#define LOG2E 1.4426950408889634f
#define QSCALE 0.18033688011112042f  // 0.125 * log2(e), folded into Q at GEMM1

typedef __attribute__((ext_vector_type(8))) short bf16x8;
typedef __attribute__((ext_vector_type(4))) float f32x4;
typedef __attribute__((ext_vector_type(8))) unsigned short u16x8;

#define B_ 2
#define T_ 2048
#define C_ 1024
#define H_ 16
#define D_ 64
#define BT_ 4096
#define N3_ 3072

#if __has_builtin(__builtin_amdgcn_exp2f)
#define EXP2(x) __builtin_amdgcn_exp2f(x)   // raw v_exp_f32 (inputs bounded, no denorm path)
#else
#define EXP2(x) exp2f(x)
#endif

__device__ __forceinline__ unsigned short f2bf(float f) {
  union { float f; unsigned u; } x; x.f = f;
  return (unsigned short)((x.u + 0x7fffu + ((x.u >> 16) & 1u)) >> 16);
}
__device__ __forceinline__ float bf2f(unsigned short u) {
  union { unsigned u; float f; } x; x.u = ((unsigned)u) << 16;
  return x.f;
}
__device__ __forceinline__ unsigned f2u(float f) {
  union { float f; unsigned u; } x; x.f = f; return x.u;
}
// pack two f32 -> dword of 2 bf16 (low short = a, high = b), round-nearest-away
__device__ __forceinline__ unsigned pack_bf2(float a, float b) {
  return __builtin_amdgcn_perm(f2u(b) + 0x8000u, f2u(a) + 0x8000u, 0x07060302u);
}

// async global->LDS 16B (m97 pattern). LDS dest must be wave-uniform base +
// lane*16 — all call sites below keep lds addr == linear(slot)*16B.
__device__ __forceinline__ void gld16(const unsigned short* g, unsigned short* l) {
  __builtin_amdgcn_global_load_lds(
      (const __attribute__((address_space(1))) unsigned int*)g,
      (__attribute__((address_space(3))) unsigned int*)l, 16, 0, 0);
}

// ---------------- prep (r11-proven): cvt + 2 transposes in one launch ---------
__device__ __forceinline__ void tr32(const float* __restrict__ in,
                                     unsigned short* __restrict__ out,
                                     int K, int N, int b, int nbx, int tid) {
  __shared__ unsigned short tile[32][33];
  const int bx = b % nbx, by = b / nbx;
  const int n0 = bx * 32, k0 = by * 32;
  const int tx = tid & 31, ty = (tid >> 5) * 4;
#pragma unroll
  for (int r = 0; r < 4; r++)
    tile[ty + r][tx] = f2bf(in[(size_t)(k0 + ty + r) * N + n0 + tx]);
  __syncthreads();
#pragma unroll
  for (int r = 0; r < 4; r++)
    out[(size_t)(n0 + ty + r) * K + k0 + tx] = tile[tx][ty + r];
}

__global__ __launch_bounds__(256) void prep_kernel(
    const float* __restrict__ x, unsigned short* __restrict__ xb,
    const float* __restrict__ wq, unsigned short* __restrict__ wqT,
    const float* __restrict__ wp, unsigned short* __restrict__ wpT) {
  const int bid = blockIdx.x, tid = threadIdx.x;
  if (bid < 4096) {
    int i = (bid * 256 + tid) * 4;
    float4 v = *(const float4*)(x + i);
    ushort4 o;
    o.x = f2bf(v.x); o.y = f2bf(v.y); o.z = f2bf(v.z); o.w = f2bf(v.w);
    *(ushort4*)(xb + i) = o;
  } else if (bid < 4096 + 3072) {
    tr32(wq, wqT, 1024, 3072, bid - 4096, 96, tid);
  } else {
    tr32(wp, wpT, 1024, 1024, bid - 7168, 32, tid);
  }
}

// ---------------- GEMM1: dual-path staging (r7) ------------------------------
// Model (r0-r6): the 2-phase gld16 structure sustains ~3.4 staged-B/cyc/BLOCK
// (r0: 24KB/7200cyc; r1: 32KB/9300; r3 counted-vmcnt: 6.8) — the LDS-DMA
// service path is the limiter, NOT L2/HBM/LDS-ports/MFMA (all <35% util).
// r7: split staging across the two independent HW paths — A (16KB) via
// vector-load->reg->ds_write_b128 (per-lane dest allowed), B (8KB) stays on
// the DMA path. Per-round critical path: max(~300cyc L2 latency + writes,
// 8KB DMA ~2400cyc) vs 24KB DMA ~7200cyc. Geometry/swizzle/barriers unchanged.
// MODE 0: scatter-write q*QSCALE [B,H,T,D], k [B,H,T,D], v [B,H,D,T] bf16
// MODE 1: write fp32 out [m][n] (N=1024)
template <int MODE>
__global__ __launch_bounds__(256) void gemm_kernel(
    const unsigned short* __restrict__ A, const unsigned short* __restrict__ Bt,
    unsigned short* __restrict__ qo, unsigned short* __restrict__ ko,
    unsigned short* __restrict__ vo, float* __restrict__ fo) {
  __shared__ unsigned short As[128 * 64];   // [row][64], chunk-swizzled
  __shared__ unsigned short Bs[64 * 64];    // [row][64], chunk-swizzled
  const int tid = threadIdx.x;
  const int wave = tid >> 6, lane = tid & 63;
  const int quad = lane >> 4, l16 = lane & 15;
  const int wm = (wave >> 1) * 64, wn = (wave & 1) * 32;
  const int m0 = blockIdx.y * 128, n0 = blockIdx.x * 64;

  f32x4 acc[4][2] = {};

  for (int k = 0; k < 1024; k += 64) {
    __syncthreads();
    // A via vector-load path (issue first, land in regs)
    uint4 areg[4];
#pragma unroll
    for (int i = 0; i < 4; i++) {
      const int s = tid + 256 * i;
      const int row = s >> 3, ch = s & 7;
      areg[i] = *(const uint4*)(A + (size_t)(m0 + row) * 1024 + k + ((ch ^ (row & 7)) * 8));
    }
    // B via LDS-DMA path (overlaps with A loads in flight)
#pragma unroll
    for (int i = 0; i < 2; i++) {
      const int s = tid + 256 * i;
      const int row = s >> 3, ch = s & 7;
      gld16(Bt + (size_t)(n0 + row) * 1024 + k + ((ch ^ (row & 7)) * 8), Bs + s * 8);
    }
#pragma unroll
    for (int i = 0; i < 4; i++)
      *(uint4*)(As + (size_t)(tid + 256 * i) * 8) = areg[i];
    __syncthreads();
#pragma unroll
    for (int sub = 0; sub < 2; sub++) {
      bf16x8 af[4], bfr[2];
#pragma unroll
      for (int mi = 0; mi < 4; mi++) {
        const int row = wm + mi * 16 + l16;
        af[mi] = *(const bf16x8*)(As + row * 64 + (((sub * 4 + quad) ^ (row & 7)) * 8));
      }
#pragma unroll
      for (int ni = 0; ni < 2; ni++) {
        const int row = wn + ni * 16 + l16;
        bfr[ni] = *(const bf16x8*)(Bs + row * 64 + (((sub * 4 + quad) ^ (row & 7)) * 8));
      }
#pragma unroll
      for (int mi = 0; mi < 4; mi++)
#pragma unroll
        for (int ni = 0; ni < 2; ni++)
          acc[mi][ni] = __builtin_amdgcn_mfma_f32_16x16x32_bf16(af[mi], bfr[ni], acc[mi][ni], 0, 0, 0);
    }
  }

  // epilogue: C/D layout col=l16, row=quad*4+r (m89/m91-verified)
  if (MODE == 0) {
    const int part = n0 >> 10;          // block-uniform
    const int hh = (n0 >> 6) & 15;      // block-uniform
#pragma unroll
    for (int mi = 0; mi < 4; mi++) {
#pragma unroll
      for (int r = 0; r < 4; r++) {
        const int m = m0 + wm + mi * 16 + quad * 4 + r;
        const int b = m >> 11, t = m & 2047;
#pragma unroll
        for (int ni = 0; ni < 2; ni++) {
          const int d = wn + ni * 16 + l16;
          float val = acc[mi][ni][r];
          if (part == 0) val *= QSCALE;   // fold softmax scale into Q (fp32, free)
          const unsigned short bv = f2bf(val);
          if (part == 0)
            qo[((size_t)(b * H_ + hh) * T_ + t) * D_ + d] = bv;
          else if (part == 1)
            ko[((size_t)(b * H_ + hh) * T_ + t) * D_ + d] = bv;
          else
            vo[((size_t)(b * H_ + hh) * D_ + d) * T_ + t] = bv;  // V pre-transposed [B,H,D,T]
        }
      }
    }
  } else {
#pragma unroll
    for (int mi = 0; mi < 4; mi++)
#pragma unroll
      for (int r = 0; r < 4; r++) {
        const int m = m0 + wm + mi * 16 + quad * 4 + r;
#pragma unroll
        for (int ni = 0; ni < 2; ni++)
          fo[(size_t)m * 1024 + n0 + wn + ni * 16 + l16] = acc[mi][ni][r];
      }
  }
}

// ---------------- GEMM2: 64x64 tile + dual-path staging (r7) -----------------
__global__ __launch_bounds__(256) void gemm2_kernel(
    const unsigned short* __restrict__ A, const unsigned short* __restrict__ Bt,
    float* __restrict__ fo) {
  __shared__ unsigned short As[64 * 64];   // 8KB, chunk-swizzled
  __shared__ unsigned short Bs[64 * 64];   // 8KB, chunk-swizzled
  const int tid = threadIdx.x;
  const int wave = tid >> 6, lane = tid & 63;
  const int quad = lane >> 4, l16 = lane & 15;
  const int wm = (wave >> 1) * 32, wn = (wave & 1) * 32;
  const int m0 = blockIdx.y * 64, n0 = blockIdx.x * 64;

  f32x4 acc[2][2] = {};

  for (int k = 0; k < 1024; k += 64) {
    __syncthreads();
    uint4 areg[2];
#pragma unroll
    for (int i = 0; i < 2; i++) {
      const int s = tid + 256 * i;
      const int row = s >> 3, ch = s & 7;
      areg[i] = *(const uint4*)(A + (size_t)(m0 + row) * 1024 + k + ((ch ^ (row & 7)) * 8));
    }
#pragma unroll
    for (int i = 0; i < 2; i++) {
      const int s = tid + 256 * i;
      const int row = s >> 3, ch = s & 7;
      gld16(Bt + (size_t)(n0 + row) * 1024 + k + ((ch ^ (row & 7)) * 8), Bs + s * 8);
    }
#pragma unroll
    for (int i = 0; i < 2; i++)
      *(uint4*)(As + (size_t)(tid + 256 * i) * 8) = areg[i];
    __syncthreads();
#pragma unroll
    for (int sub = 0; sub < 2; sub++) {
      bf16x8 af[2], bfr[2];
#pragma unroll
      for (int mi = 0; mi < 2; mi++) {
        const int row = wm + mi * 16 + l16;
        af[mi] = *(const bf16x8*)(As + row * 64 + (((sub * 4 + quad) ^ (row & 7)) * 8));
      }
#pragma unroll
      for (int ni = 0; ni < 2; ni++) {
        const int row = wn + ni * 16 + l16;
        bfr[ni] = *(const bf16x8*)(Bs + row * 64 + (((sub * 4 + quad) ^ (row & 7)) * 8));
      }
#pragma unroll
      for (int mi = 0; mi < 2; mi++)
#pragma unroll
        for (int ni = 0; ni < 2; ni++)
          acc[mi][ni] = __builtin_amdgcn_mfma_f32_16x16x32_bf16(af[mi], bfr[ni], acc[mi][ni], 0, 0, 0);
    }
  }

  // epilogue: C/D layout col=l16, row=quad*4+r
#pragma unroll
  for (int mi = 0; mi < 2; mi++)
#pragma unroll
    for (int r = 0; r < 4; r++) {
      const int m = m0 + wm + mi * 16 + quad * 4 + r;
#pragma unroll
      for (int ni = 0; ni < 2; ni++)
        fo[(size_t)m * 1024 + n0 + wn + ni * 16 + l16] = acc[mi][ni][r];
    }
}

// ---------------- flash attention: Q-tile 128, 8 waves (r6) + dual-path (r7) --
// K staged via reg path (load issued BEFORE barrier1 -> latency under previous
// PV compute; ds_write after barrier), V stays on the DMA path.
__device__ const unsigned char CHUNK_TAB[30] = {
    // (qs<<4)|(c<<2)|nch, sorted by chunk length desc
    0x71, 0x61, 0x51, 0xF7, 0xFB, 0x41, 0x92, 0x96, 0xDB, 0xE3,
    0xE7, 0xEB, 0xF3, 0x82, 0x86, 0xC7, 0xCB, 0xD3, 0xD7, 0x31,
    0xAB, 0xB3, 0xB7, 0xBB, 0xC3, 0xA3, 0xA7, 0x21, 0x11, 0x01};

__global__ __launch_bounds__(512) void attn_kernel(
    const unsigned short* __restrict__ qb, const unsigned short* __restrict__ kb,
    const unsigned short* __restrict__ vb, unsigned short* __restrict__ yb,
    unsigned short* __restrict__ po, float* __restrict__ pl) {
  const int tid = threadIdx.x;
  const int wave = tid >> 6, lane = tid & 63;
  const int quad = lane >> 4, l16 = lane & 15;

  const int bid = blockIdx.x;
  const int bh = bid & 31;          // XCD-local: all chunks of bh on one XCD
  const int u = bid >> 5;           // 0..29, longest chunks first
  const int e = CHUNK_TAB[u];
  const int qs = e >> 4, c = (e >> 2) & 3, nch = e & 3;
  const int nt = 2 * qs + 2;
  const int j0 = c * nt / nch, j1 = (c + 1) * nt / nch;
  const int b = bh >> 4, h = bh & 15;

  __shared__ unsigned short Ks[64 * 64];     // [s][d], chunk-swizzled, 8KB
  __shared__ unsigned short Vt[64 * 64];     // [d][s], chunk-swizzled, 8KB
  __shared__ unsigned short Ps[8 * 16 * 68]; // per-wave P [q][s], stride 68
  unsigned short* Pw = Ps + wave * 16 * 68;

  const unsigned short* Qg = qb + (size_t)bh * T_ * D_;
  const unsigned short* Kg = kb + (size_t)bh * T_ * D_;
  const unsigned short* Vg = vb + (size_t)bh * D_ * T_;

  // Q fragment (B-operand: n=q=l16, k=d=quad*8+j); wave owns 16 q-rows
  const int qrow0 = qs * 128 + wave * 16;
  const unsigned short* qp = Qg + (size_t)(qrow0 + l16) * D_ + quad * 8;
  bf16x8 qf0 = *(const bf16x8*)qp, qf1 = *(const bf16x8*)(qp + 32);

  f32x4 o[4] = {};
  float lacc = 0.f;
  const int qglob = qrow0 + l16;                 // this lane's q (S^T: col=l16)
  const int sloc_base = quad * 4;                // s-local row base (S^T: row=quad*4+r)
  const int diag0 = 2 * qs;                      // first tile needing masking

  const int trow = tid >> 3, tch = tid & 7;      // 512 thr: rows 0..63, ch 0..7

  for (int jt = j0; jt < j1; jt++) {
    const int s0 = jt * 64;
    // K via reg path: issue before the barrier (covered by previous compute)
    uint4 kreg = *(const uint4*)(Kg + (size_t)(s0 + trow) * D_ + ((tch ^ (trow & 7)) * 8));
    __syncthreads();
    // V via DMA path
    gld16(Vg + (size_t)trow * T_ + s0 + ((tch ^ (trow & 7)) * 8), Vt + trow * 64 + tch * 8);
    *(uint4*)(Ks + (size_t)trow * 64 + tch * 8) = kreg;
    __syncthreads();

    // S^T = K Q^T : K as A-operand, Q as B-operand.
    // C-layout of s[mi]: row = s-local = mi*16+quad*4+r, col = q = l16.
    f32x4 s[4];
#pragma unroll
    for (int mi = 0; mi < 4; mi++) {
      const int row = mi * 16 + l16, sw = row & 7;
      bf16x8 kf0 = *(const bf16x8*)(Ks + row * 64 + ((quad ^ sw) * 8));
      bf16x8 kf1 = *(const bf16x8*)(Ks + row * 64 + (((quad + 4) ^ sw) * 8));
      f32x4 z = {0.f, 0.f, 0.f, 0.f};
      z = __builtin_amdgcn_mfma_f32_16x16x32_bf16(kf0, qf0, z, 0, 0, 0);
      s[mi] = __builtin_amdgcn_mfma_f32_16x16x32_bf16(kf1, qf1, z, 0, 0, 0);
    }

    if (jt >= diag0) {  // uniform diag branch: mask s > q (both diagonal tiles)
#pragma unroll
      for (int mi = 0; mi < 4; mi++)
#pragma unroll
        for (int r = 0; r < 4; r++) {
          float p = EXP2(s[mi][r]);
          p = (s0 + mi * 16 + sloc_base + r > qglob) ? 0.f : p;
          s[mi][r] = p;
          lacc += p;
        }
    } else {
#pragma unroll
      for (int mi = 0; mi < 4; mi++)
#pragma unroll
        for (int r = 0; r < 4; r++) {
          float p = EXP2(s[mi][r]);
          s[mi][r] = p;
          lacc += p;
        }
    }

    // P -> LDS [q=l16][s], packed dwords
#pragma unroll
    for (int mi = 0; mi < 4; mi++) {
      unsigned d0 = pack_bf2(s[mi][0], s[mi][1]);
      unsigned d1 = pack_bf2(s[mi][2], s[mi][3]);
      *(uint2*)(Pw + l16 * 68 + mi * 16 + quad * 4) = make_uint2(d0, d1);
    }

    // O += P V : P as A-operand (m=q=l16, k=s), V^T as B-operand
#pragma unroll
    for (int kk = 0; kk < 2; kk++) {
      bf16x8 pf = *(const bf16x8*)(Pw + l16 * 68 + kk * 32 + quad * 8);
#pragma unroll
      for (int ni = 0; ni < 4; ni++) {
        const int row = ni * 16 + l16, sw = row & 7;
        bf16x8 vf = *(const bf16x8*)(Vt + row * 64 + (((kk * 4 + quad) ^ sw) * 8));
        o[ni] = __builtin_amdgcn_mfma_f32_16x16x32_bf16(pf, vf, o[ni], 0, 0, 0);
      }
    }
  }

  // l: sum across the 4 lanes sharing l16 (quads), then fetch per-row values
  lacc += __shfl_xor(lacc, 16, 64);
  lacc += __shfl_xor(lacc, 32, 64);
  float lr[4];
#pragma unroll
  for (int r = 0; r < 4; r++) lr[r] = __shfl(lacc, quad * 4 + r, 16);  // l for q-row quad*4+r

  if (nch == 1) {
#pragma unroll
    for (int r = 0; r < 4; r++) {
      float inv = 1.0f / lr[r];
      int tq = qrow0 + quad * 4 + r;
#pragma unroll
      for (int ni = 0; ni < 4; ni++)
        yb[((size_t)(b * T_ + tq)) * 1024 + h * 64 + ni * 16 + l16] = f2bf(o[ni][r] * inv);
    }
  } else {
    // split slots: qs 8,9 -> (qs-8)*2 + c; qs 10..15 -> 4 + (qs-10)*3 + c
    const int slot = 22 * bh + ((qs < 10) ? ((qs - 8) * 2 + c) : (4 + (qs - 10) * 3 + c));
    unsigned short* pob = po + (size_t)slot * 8192;
#pragma unroll
    for (int r = 0; r < 4; r++) {
      const int row128 = wave * 16 + quad * 4 + r;
#pragma unroll
      for (int ni = 0; ni < 4; ni++)
        pob[row128 * 64 + ni * 16 + l16] = f2bf(o[ni][r]);
      if (l16 == 0) pl[slot * 128 + row128] = lr[r];
    }
  }
}

// ---------------- split-K reduce: q-blocks qs>=8 (128 rows each) --------------
__global__ __launch_bounds__(256) void reduce_kernel(
    const unsigned short* __restrict__ po, const float* __restrict__ pl,
    unsigned short* __restrict__ yb) {
  int idx = blockIdx.x * 256 + threadIdx.x;   // 32 bh * 8 qsplit * 128 rows * 16 cg
  int bh = idx >> 14;
  int rem = idx & 16383;
  int qs = 8 + (rem >> 11);
  int row128 = (rem >> 4) & 127;
  int cg = rem & 15;
  int base, nch;
  if (qs < 10) { base = (qs - 8) * 2; nch = 2; }
  else { base = 4 + (qs - 10) * 3; nch = 3; }
  int b = bh >> 4, h = bh & 15;
  float a0 = 0.f, a1 = 0.f, a2 = 0.f, a3 = 0.f, l = 0.f;
  for (int cc = 0; cc < nch; cc++) {
    int slot = 22 * bh + base + cc;
    const unsigned short* p = po + (size_t)slot * 8192 + row128 * 64 + cg * 4;
    ushort4 uv = *(const ushort4*)p;
    a0 += bf2f(uv.x); a1 += bf2f(uv.y); a2 += bf2f(uv.z); a3 += bf2f(uv.w);
    l += pl[slot * 128 + row128];
  }
  float inv = 1.0f / l;
  int tq = qs * 128 + row128;
  ushort4 w;
  w.x = f2bf(a0 * inv); w.y = f2bf(a1 * inv); w.z = f2bf(a2 * inv); w.w = f2bf(a3 * inv);
  *(ushort4*)(yb + ((size_t)(b * T_ + tq)) * 1024 + h * 64 + cg * 4) = w;
}

// ---------------- launch ----------------
extern "C" void kernel_launch(void* const* d_in, const int* in_sizes, int n_in,
                              void* d_out, int out_size, void* d_ws, size_t ws_size,
                              hipStream_t stream) {
  const float* x = (const float*)d_in[0];       // [B,T,C]
  const float* w_qkv = (const float*)d_in[1];   // [C,3C]
  const float* w_proj = (const float*)d_in[2];  // [C,C]
  float* out = (float*)d_out;                   // [B,T,C] fp32

  // ws layout (shorts). po aliases wqkvT (dead after GEMM1). ~47.6 MB total.
  unsigned short* xb = (unsigned short*)d_ws;                 // 4.19M shorts
  unsigned short* wprojT = xb + (size_t)BT_ * C_;             // 1.05M
  unsigned short* qb = wprojT + (size_t)C_ * C_;              // 4.19M
  unsigned short* kb = qb + (size_t)B_ * H_ * T_ * D_;        // 4.19M
  unsigned short* vb = kb + (size_t)B_ * H_ * T_ * D_;        // 4.19M
  unsigned short* wqkvT = vb + (size_t)B_ * H_ * T_ * D_;     // 3.15M
  unsigned short* po = wqkvT;                                 // 704 slots * 8192 = 5.77M
  float* pl = (float*)(po + (size_t)704 * 8192);              // 90K fp32
  unsigned short* yb = xb;  // reuse (x dead after GEMM1)

  prep_kernel<<<dim3(8192), 256, 0, stream>>>(x, xb, w_qkv, wqkvT, w_proj, wprojT);

  gemm_kernel<0><<<dim3(N3_ / 64, BT_ / 128), 256, 0, stream>>>(xb, wqkvT, qb, kb, vb, nullptr);
  attn_kernel<<<dim3(32 * 30), 512, 0, stream>>>(qb, kb, vb, yb, po, pl);
  reduce_kernel<<<dim3(2048), 256, 0, stream>>>(po, pl, yb);
  gemm2_kernel<<<dim3(C_ / 64, BT_ / 64), 256, 0, stream>>>(yb, wprojT, out);
}

// Round 8
// 185.944 us; speedup vs baseline: 1.0067x; 1.0067x over previous
//
#include <hip/hip_runtime.h>
#include <stdint.h>

#define LOG2E 1.4426950408889634f
#define QSCALE 0.18033688011112042f  // 0.125 * log2(e), folded into Q at GEMM1

typedef __attribute__((ext_vector_type(8))) short bf16x8;
typedef __attribute__((ext_vector_type(4))) float f32x4;
typedef __attribute__((ext_vector_type(8))) unsigned short u16x8;

#define B_ 2
#define T_ 2048
#define C_ 1024
#define H_ 16
#define D_ 64
#define BT_ 4096
#define N3_ 3072

#if __has_builtin(__builtin_amdgcn_exp2f)
#define EXP2(x) __builtin_amdgcn_exp2f(x)   // raw v_exp_f32 (inputs bounded, no denorm path)
#else
#define EXP2(x) exp2f(x)
#endif

__device__ __forceinline__ unsigned short f2bf(float f) {
  union { float f; unsigned u; } x; x.f = f;
  return (unsigned short)((x.u + 0x7fffu + ((x.u >> 16) & 1u)) >> 16);
}
__device__ __forceinline__ float bf2f(unsigned short u) {
  union { unsigned u; float f; } x; x.u = ((unsigned)u) << 16;
  return x.f;
}
__device__ __forceinline__ unsigned f2u(float f) {
  union { float f; unsigned u; } x; x.f = f; return x.u;
}
// pack two f32 -> dword of 2 bf16 (low short = a, high = b), round-nearest-away
__device__ __forceinline__ unsigned pack_bf2(float a, float b) {
  return __builtin_amdgcn_perm(f2u(b) + 0x8000u, f2u(a) + 0x8000u, 0x07060302u);
}

// async global->LDS 16B (m97 pattern). LDS dest must be wave-uniform base +
// lane*16 — all call sites below keep lds addr == linear(slot)*16B.
__device__ __forceinline__ void gld16(const unsigned short* g, unsigned short* l) {
  __builtin_amdgcn_global_load_lds(
      (const __attribute__((address_space(1))) unsigned int*)g,
      (__attribute__((address_space(3))) unsigned int*)l, 16, 0, 0);
}

// ---------------- prep (r11-proven): cvt + 2 transposes in one launch ---------
__device__ __forceinline__ void tr32(const float* __restrict__ in,
                                     unsigned short* __restrict__ out,
                                     int K, int N, int b, int nbx, int tid) {
  __shared__ unsigned short tile[32][33];
  const int bx = b % nbx, by = b / nbx;
  const int n0 = bx * 32, k0 = by * 32;
  const int tx = tid & 31, ty = (tid >> 5) * 4;
#pragma unroll
  for (int r = 0; r < 4; r++)
    tile[ty + r][tx] = f2bf(in[(size_t)(k0 + ty + r) * N + n0 + tx]);
  __syncthreads();
#pragma unroll
  for (int r = 0; r < 4; r++)
    out[(size_t)(n0 + ty + r) * K + k0 + tx] = tile[tx][ty + r];
}

__global__ __launch_bounds__(256) void prep_kernel(
    const float* __restrict__ x, unsigned short* __restrict__ xb,
    const float* __restrict__ wq, unsigned short* __restrict__ wqT,
    const float* __restrict__ wp, unsigned short* __restrict__ wpT) {
  const int bid = blockIdx.x, tid = threadIdx.x;
  if (bid < 4096) {
    int i = (bid * 256 + tid) * 4;
    float4 v = *(const float4*)(x + i);
    ushort4 o;
    o.x = f2bf(v.x); o.y = f2bf(v.y); o.z = f2bf(v.z); o.w = f2bf(v.w);
    *(ushort4*)(xb + i) = o;
  } else if (bid < 4096 + 3072) {
    tr32(wq, wqT, 1024, 3072, bid - 4096, 96, tid);
  } else {
    tr32(wp, wpT, 1024, 1024, bid - 7168, 32, tid);
  }
}

// ---------------- GEMM1: 128x128, 512 thr / 8 staging waves (r8) -------------
// Per-wave staging law (fits r0/r1/r3/r5 exactly): each wave sustains ~0.85
// staged-B/cyc through gld16; kernel time ~= per-wave staged bytes / 0.85.
// r0: 384KB tile / 4 waves = 96KB -> 47us. r1 (128^2, 4 waves): 128KB -> 62us.
// Here: 128^2 tile / 8 waves = 64KB/wave -> ~31us predicted. Wave-grid 2x4,
// per-wave 64x32 output = r0's exact acc[4][2] shape. LDS 32KB, grid 768 = 3/CU
// (4 resident capacity). 2-phase body otherwise byte-identical to r0.
// Scatter-write q*QSCALE [B,H,T,D], k [B,H,T,D], v [B,H,D,T] bf16.
__global__ __launch_bounds__(512) void gemm_kernel(
    const unsigned short* __restrict__ A, const unsigned short* __restrict__ Bt,
    unsigned short* __restrict__ qo, unsigned short* __restrict__ ko,
    unsigned short* __restrict__ vo) {
  __shared__ unsigned short As[128 * 64];   // [row][64], chunk-swizzled, 16KB
  __shared__ unsigned short Bs[128 * 64];   // [row][64], chunk-swizzled, 16KB
  const int tid = threadIdx.x;
  const int wave = tid >> 6, lane = tid & 63;
  const int quad = lane >> 4, l16 = lane & 15;
  const int wm = (wave >> 2) * 64, wn = (wave & 3) * 32;
  const int m0 = blockIdx.y * 128, n0 = blockIdx.x * 128;

  f32x4 acc[4][2] = {};

  for (int k = 0; k < 1024; k += 64) {
    __syncthreads();
#pragma unroll
    for (int i = 0; i < 2; i++) {
      const int s = tid + 512 * i;          // 0..1023
      const int row = s >> 3, ch = s & 7;   // 128 rows x 8 chunks
      gld16(A + (size_t)(m0 + row) * 1024 + k + ((ch ^ (row & 7)) * 8), As + s * 8);
      gld16(Bt + (size_t)(n0 + row) * 1024 + k + ((ch ^ (row & 7)) * 8), Bs + s * 8);
    }
    __syncthreads();
#pragma unroll
    for (int sub = 0; sub < 2; sub++) {
      bf16x8 af[4], bfr[2];
#pragma unroll
      for (int mi = 0; mi < 4; mi++) {
        const int row = wm + mi * 16 + l16;
        af[mi] = *(const bf16x8*)(As + row * 64 + (((sub * 4 + quad) ^ (row & 7)) * 8));
      }
#pragma unroll
      for (int ni = 0; ni < 2; ni++) {
        const int row = wn + ni * 16 + l16;
        bfr[ni] = *(const bf16x8*)(Bs + row * 64 + (((sub * 4 + quad) ^ (row & 7)) * 8));
      }
#pragma unroll
      for (int mi = 0; mi < 4; mi++)
#pragma unroll
        for (int ni = 0; ni < 2; ni++)
          acc[mi][ni] = __builtin_amdgcn_mfma_f32_16x16x32_bf16(af[mi], bfr[ni], acc[mi][ni], 0, 0, 0);
    }
  }

  // epilogue: C/D layout col=l16, row=quad*4+r (m89/m91-verified).
  // n0 multiple of 128 -> part uniform (1024%128==0); per-wave 32 cols sit
  // inside one head: hh from (n0+wn), d = (wn&63)+ni*16+l16 < 64.
  const int part = n0 >> 10;
  const int hh = ((n0 + wn) >> 6) & 15;
  const int dbase = (wn & 63);
#pragma unroll
  for (int mi = 0; mi < 4; mi++) {
#pragma unroll
    for (int r = 0; r < 4; r++) {
      const int m = m0 + wm + mi * 16 + quad * 4 + r;
      const int b = m >> 11, t = m & 2047;
#pragma unroll
      for (int ni = 0; ni < 2; ni++) {
        const int d = dbase + ni * 16 + l16;
        float val = acc[mi][ni][r];
        if (part == 0) val *= QSCALE;   // fold softmax scale into Q (fp32, free)
        const unsigned short bv = f2bf(val);
        if (part == 0)
          qo[((size_t)(b * H_ + hh) * T_ + t) * D_ + d] = bv;
        else if (part == 1)
          ko[((size_t)(b * H_ + hh) * T_ + t) * D_ + d] = bv;
        else
          vo[((size_t)(b * H_ + hh) * D_ + d) * T_ + t] = bv;  // V pre-transposed [B,H,D,T]
      }
    }
  }
}

// ---------------- GEMM2: 64x64, 512 thr / 8 staging waves (r8) ---------------
// Same law: 256KB tile / 8 waves = 32KB/wave -> ~16us predicted. Wave-grid 2x4,
// per-wave 32x16 output acc[2]. LDS 16KB; grid 1024 = 4/CU = resident capacity.
__global__ __launch_bounds__(512) void gemm2_kernel(
    const unsigned short* __restrict__ A, const unsigned short* __restrict__ Bt,
    float* __restrict__ fo) {
  __shared__ unsigned short As[64 * 64];   // 8KB, chunk-swizzled
  __shared__ unsigned short Bs[64 * 64];   // 8KB, chunk-swizzled
  const int tid = threadIdx.x;
  const int wave = tid >> 6, lane = tid & 63;
  const int quad = lane >> 4, l16 = lane & 15;
  const int wm = (wave >> 2) * 32, wn = (wave & 3) * 16;
  const int m0 = blockIdx.y * 64, n0 = blockIdx.x * 64;

  f32x4 acc[2] = {};

  for (int k = 0; k < 1024; k += 64) {
    __syncthreads();
    {
      const int s = tid;                    // 0..511
      const int row = s >> 3, ch = s & 7;   // 64 rows x 8 chunks
      gld16(A + (size_t)(m0 + row) * 1024 + k + ((ch ^ (row & 7)) * 8), As + s * 8);
      gld16(Bt + (size_t)(n0 + row) * 1024 + k + ((ch ^ (row & 7)) * 8), Bs + s * 8);
    }
    __syncthreads();
#pragma unroll
    for (int sub = 0; sub < 2; sub++) {
      bf16x8 af[2], bfr;
#pragma unroll
      for (int mi = 0; mi < 2; mi++) {
        const int row = wm + mi * 16 + l16;
        af[mi] = *(const bf16x8*)(As + row * 64 + (((sub * 4 + quad) ^ (row & 7)) * 8));
      }
      {
        const int row = wn + l16;
        bfr = *(const bf16x8*)(Bs + row * 64 + (((sub * 4 + quad) ^ (row & 7)) * 8));
      }
#pragma unroll
      for (int mi = 0; mi < 2; mi++)
        acc[mi] = __builtin_amdgcn_mfma_f32_16x16x32_bf16(af[mi], bfr, acc[mi], 0, 0, 0);
    }
  }

  // epilogue: C/D layout col=l16, row=quad*4+r
#pragma unroll
  for (int mi = 0; mi < 2; mi++)
#pragma unroll
    for (int r = 0; r < 4; r++) {
      const int m = m0 + wm + mi * 16 + quad * 4 + r;
      fo[(size_t)m * 1024 + n0 + wn + l16] = acc[mi][r];
    }
}

// ---------------- flash attention: Q-tile 128, 8 waves (r6 exact revert) ------
__device__ const unsigned char CHUNK_TAB[30] = {
    // (qs<<4)|(c<<2)|nch, sorted by chunk length desc
    0x71, 0x61, 0x51, 0xF7, 0xFB, 0x41, 0x92, 0x96, 0xDB, 0xE3,
    0xE7, 0xEB, 0xF3, 0x82, 0x86, 0xC7, 0xCB, 0xD3, 0xD7, 0x31,
    0xAB, 0xB3, 0xB7, 0xBB, 0xC3, 0xA3, 0xA7, 0x21, 0x11, 0x01};

__global__ __launch_bounds__(512) void attn_kernel(
    const unsigned short* __restrict__ qb, const unsigned short* __restrict__ kb,
    const unsigned short* __restrict__ vb, unsigned short* __restrict__ yb,
    unsigned short* __restrict__ po, float* __restrict__ pl) {
  const int tid = threadIdx.x;
  const int wave = tid >> 6, lane = tid & 63;
  const int quad = lane >> 4, l16 = lane & 15;

  const int bid = blockIdx.x;
  const int bh = bid & 31;          // XCD-local: all chunks of bh on one XCD
  const int u = bid >> 5;           // 0..29, longest chunks first
  const int e = CHUNK_TAB[u];
  const int qs = e >> 4, c = (e >> 2) & 3, nch = e & 3;
  const int nt = 2 * qs + 2;
  const int j0 = c * nt / nch, j1 = (c + 1) * nt / nch;
  const int b = bh >> 4, h = bh & 15;

  __shared__ unsigned short Ks[64 * 64];     // [s][d], chunk-swizzled, 8KB
  __shared__ unsigned short Vt[64 * 64];     // [d][s], chunk-swizzled, 8KB
  __shared__ unsigned short Ps[8 * 16 * 68]; // per-wave P [q][s], stride 68
  unsigned short* Pw = Ps + wave * 16 * 68;

  const unsigned short* Qg = qb + (size_t)bh * T_ * D_;
  const unsigned short* Kg = kb + (size_t)bh * T_ * D_;
  const unsigned short* Vg = vb + (size_t)bh * D_ * T_;

  // Q fragment (B-operand: n=q=l16, k=d=quad*8+j); wave owns 16 q-rows
  const int qrow0 = qs * 128 + wave * 16;
  const unsigned short* qp = Qg + (size_t)(qrow0 + l16) * D_ + quad * 8;
  bf16x8 qf0 = *(const bf16x8*)qp, qf1 = *(const bf16x8*)(qp + 32);

  f32x4 o[4] = {};
  float lacc = 0.f;
  const int qglob = qrow0 + l16;                 // this lane's q (S^T: col=l16)
  const int sloc_base = quad * 4;                // s-local row base (S^T: row=quad*4+r)
  const int diag0 = 2 * qs;                      // first tile needing masking

  const int trow = tid >> 3, tch = tid & 7;      // 512 thr: rows 0..63, ch 0..7

  for (int jt = j0; jt < j1; jt++) {
    const int s0 = jt * 64;
    __syncthreads();
    {
      gld16(Kg + (size_t)(s0 + trow) * D_ + ((tch ^ (trow & 7)) * 8), Ks + trow * 64 + tch * 8);
      gld16(Vg + (size_t)trow * T_ + s0 + ((tch ^ (trow & 7)) * 8), Vt + trow * 64 + tch * 8);
    }
    __syncthreads();

    // S^T = K Q^T : K as A-operand, Q as B-operand.
    // C-layout of s[mi]: row = s-local = mi*16+quad*4+r, col = q = l16.
    f32x4 s[4];
#pragma unroll
    for (int mi = 0; mi < 4; mi++) {
      const int row = mi * 16 + l16, sw = row & 7;
      bf16x8 kf0 = *(const bf16x8*)(Ks + row * 64 + ((quad ^ sw) * 8));
      bf16x8 kf1 = *(const bf16x8*)(Ks + row * 64 + (((quad + 4) ^ sw) * 8));
      f32x4 z = {0.f, 0.f, 0.f, 0.f};
      z = __builtin_amdgcn_mfma_f32_16x16x32_bf16(kf0, qf0, z, 0, 0, 0);
      s[mi] = __builtin_amdgcn_mfma_f32_16x16x32_bf16(kf1, qf1, z, 0, 0, 0);
    }

    if (jt >= diag0) {  // uniform diag branch: mask s > q (both diagonal tiles)
#pragma unroll
      for (int mi = 0; mi < 4; mi++)
#pragma unroll
        for (int r = 0; r < 4; r++) {
          float p = EXP2(s[mi][r]);
          p = (s0 + mi * 16 + sloc_base + r > qglob) ? 0.f : p;
          s[mi][r] = p;
          lacc += p;
        }
    } else {
#pragma unroll
      for (int mi = 0; mi < 4; mi++)
#pragma unroll
        for (int r = 0; r < 4; r++) {
          float p = EXP2(s[mi][r]);
          s[mi][r] = p;
          lacc += p;
        }
    }

    // P -> LDS [q=l16][s], packed dwords
#pragma unroll
    for (int mi = 0; mi < 4; mi++) {
      unsigned d0 = pack_bf2(s[mi][0], s[mi][1]);
      unsigned d1 = pack_bf2(s[mi][2], s[mi][3]);
      *(uint2*)(Pw + l16 * 68 + mi * 16 + quad * 4) = make_uint2(d0, d1);
    }

    // O += P V : P as A-operand (m=q=l16, k=s), V^T as B-operand
#pragma unroll
    for (int kk = 0; kk < 2; kk++) {
      bf16x8 pf = *(const bf16x8*)(Pw + l16 * 68 + kk * 32 + quad * 8);
#pragma unroll
      for (int ni = 0; ni < 4; ni++) {
        const int row = ni * 16 + l16, sw = row & 7;
        bf16x8 vf = *(const bf16x8*)(Vt + row * 64 + (((kk * 4 + quad) ^ sw) * 8));
        o[ni] = __builtin_amdgcn_mfma_f32_16x16x32_bf16(pf, vf, o[ni], 0, 0, 0);
      }
    }
  }

  // l: sum across the 4 lanes sharing l16 (quads), then fetch per-row values
  lacc += __shfl_xor(lacc, 16, 64);
  lacc += __shfl_xor(lacc, 32, 64);
  float lr[4];
#pragma unroll
  for (int r = 0; r < 4; r++) lr[r] = __shfl(lacc, quad * 4 + r, 16);  // l for q-row quad*4+r

  if (nch == 1) {
#pragma unroll
    for (int r = 0; r < 4; r++) {
      float inv = 1.0f / lr[r];
      int tq = qrow0 + quad * 4 + r;
#pragma unroll
      for (int ni = 0; ni < 4; ni++)
        yb[((size_t)(b * T_ + tq)) * 1024 + h * 64 + ni * 16 + l16] = f2bf(o[ni][r] * inv);
    }
  } else {
    // split slots: qs 8,9 -> (qs-8)*2 + c; qs 10..15 -> 4 + (qs-10)*3 + c
    const int slot = 22 * bh + ((qs < 10) ? ((qs - 8) * 2 + c) : (4 + (qs - 10) * 3 + c));
    unsigned short* pob = po + (size_t)slot * 8192;
#pragma unroll
    for (int r = 0; r < 4; r++) {
      const int row128 = wave * 16 + quad * 4 + r;
#pragma unroll
      for (int ni = 0; ni < 4; ni++)
        pob[row128 * 64 + ni * 16 + l16] = f2bf(o[ni][r]);
      if (l16 == 0) pl[slot * 128 + row128] = lr[r];
    }
  }
}

// ---------------- split-K reduce: q-blocks qs>=8 (128 rows each) --------------
__global__ __launch_bounds__(256) void reduce_kernel(
    const unsigned short* __restrict__ po, const float* __restrict__ pl,
    unsigned short* __restrict__ yb) {
  int idx = blockIdx.x * 256 + threadIdx.x;   // 32 bh * 8 qsplit * 128 rows * 16 cg
  int bh = idx >> 14;
  int rem = idx & 16383;
  int qs = 8 + (rem >> 11);
  int row128 = (rem >> 4) & 127;
  int cg = rem & 15;
  int base, nch;
  if (qs < 10) { base = (qs - 8) * 2; nch = 2; }
  else { base = 4 + (qs - 10) * 3; nch = 3; }
  int b = bh >> 4, h = bh & 15;
  float a0 = 0.f, a1 = 0.f, a2 = 0.f, a3 = 0.f, l = 0.f;
  for (int cc = 0; cc < nch; cc++) {
    int slot = 22 * bh + base + cc;
    const unsigned short* p = po + (size_t)slot * 8192 + row128 * 64 + cg * 4;
    ushort4 uv = *(const ushort4*)p;
    a0 += bf2f(uv.x); a1 += bf2f(uv.y); a2 += bf2f(uv.z); a3 += bf2f(uv.w);
    l += pl[slot * 128 + row128];
  }
  float inv = 1.0f / l;
  int tq = qs * 128 + row128;
  ushort4 w;
  w.x = f2bf(a0 * inv); w.y = f2bf(a1 * inv); w.z = f2bf(a2 * inv); w.w = f2bf(a3 * inv);
  *(ushort4*)(yb + ((size_t)(b * T_ + tq)) * 1024 + h * 64 + cg * 4) = w;
}

// ---------------- launch ----------------
extern "C" void kernel_launch(void* const* d_in, const int* in_sizes, int n_in,
                              void* d_out, int out_size, void* d_ws, size_t ws_size,
                              hipStream_t stream) {
  const float* x = (const float*)d_in[0];       // [B,T,C]
  const float* w_qkv = (const float*)d_in[1];   // [C,3C]
  const float* w_proj = (const float*)d_in[2];  // [C,C]
  float* out = (float*)d_out;                   // [B,T,C] fp32

  // ws layout (shorts). po aliases wqkvT (dead after GEMM1). ~47.6 MB total.
  unsigned short* xb = (unsigned short*)d_ws;                 // 4.19M shorts
  unsigned short* wprojT = xb + (size_t)BT_ * C_;             // 1.05M
  unsigned short* qb = wprojT + (size_t)C_ * C_;              // 4.19M
  unsigned short* kb = qb + (size_t)B_ * H_ * T_ * D_;        // 4.19M
  unsigned short* vb = kb + (size_t)B_ * H_ * T_ * D_;        // 4.19M
  unsigned short* wqkvT = vb + (size_t)B_ * H_ * T_ * D_;     // 3.15M
  unsigned short* po = wqkvT;                                 // 704 slots * 8192 = 5.77M
  float* pl = (float*)(po + (size_t)704 * 8192);              // 90K fp32
  unsigned short* yb = xb;  // reuse (x dead after GEMM1)

  prep_kernel<<<dim3(8192), 256, 0, stream>>>(x, xb, w_qkv, wqkvT, w_proj, wprojT);

  gemm_kernel<<<dim3(N3_ / 128, BT_ / 128), 512, 0, stream>>>(xb, wqkvT, qb, kb, vb);
  attn_kernel<<<dim3(32 * 30), 512, 0, stream>>>(qb, kb, vb, yb, po, pl);
  reduce_kernel<<<dim3(2048), 256, 0, stream>>>(po, pl, yb);
  gemm2_kernel<<<dim3(C_ / 64, BT_ / 64), 512, 0, stream>>>(yb, wprojT, out);
}

// Round 9
// 180.368 us; speedup vs baseline: 1.0378x; 1.0309x over previous
//
#include <hip/hip_runtime.h>
#include <stdint.h>

#define LOG2E 1.4426950408889634f
#define QSCALE 0.18033688011112042f  // 0.125 * log2(e), folded into Q at GEMM1

typedef __attribute__((ext_vector_type(8))) short bf16x8;
typedef __attribute__((ext_vector_type(4))) float f32x4;
typedef __attribute__((ext_vector_type(8))) unsigned short u16x8;

#define B_ 2
#define T_ 2048
#define C_ 1024
#define H_ 16
#define D_ 64
#define BT_ 4096
#define N3_ 3072

#if __has_builtin(__builtin_amdgcn_exp2f)
#define EXP2(x) __builtin_amdgcn_exp2f(x)   // raw v_exp_f32 (inputs bounded, no denorm path)
#else
#define EXP2(x) exp2f(x)
#endif

__device__ __forceinline__ unsigned short f2bf(float f) {
  union { float f; unsigned u; } x; x.f = f;
  return (unsigned short)((x.u + 0x7fffu + ((x.u >> 16) & 1u)) >> 16);
}
__device__ __forceinline__ float bf2f(unsigned short u) {
  union { unsigned u; float f; } x; x.u = ((unsigned)u) << 16;
  return x.f;
}
__device__ __forceinline__ unsigned f2u(float f) {
  union { float f; unsigned u; } x; x.f = f; return x.u;
}
// pack two f32 -> dword of 2 bf16 (low short = a, high = b), round-nearest-away
__device__ __forceinline__ unsigned pack_bf2(float a, float b) {
  return __builtin_amdgcn_perm(f2u(b) + 0x8000u, f2u(a) + 0x8000u, 0x07060302u);
}

// async global->LDS 16B (m97 pattern). LDS dest must be wave-uniform base +
// lane*16 — all call sites below keep lds addr == linear(slot)*16B.
__device__ __forceinline__ void gld16(const unsigned short* g, unsigned short* l) {
  __builtin_amdgcn_global_load_lds(
      (const __attribute__((address_space(1))) unsigned int*)g,
      (__attribute__((address_space(3))) unsigned int*)l, 16, 0, 0);
}

// ---------------- prep (r11-proven): cvt + 2 transposes in one launch ---------
__device__ __forceinline__ void tr32(const float* __restrict__ in,
                                     unsigned short* __restrict__ out,
                                     int K, int N, int b, int nbx, int tid) {
  __shared__ unsigned short tile[32][33];
  const int bx = b % nbx, by = b / nbx;
  const int n0 = bx * 32, k0 = by * 32;
  const int tx = tid & 31, ty = (tid >> 5) * 4;
#pragma unroll
  for (int r = 0; r < 4; r++)
    tile[ty + r][tx] = f2bf(in[(size_t)(k0 + ty + r) * N + n0 + tx]);
  __syncthreads();
#pragma unroll
  for (int r = 0; r < 4; r++)
    out[(size_t)(n0 + ty + r) * K + k0 + tx] = tile[tx][ty + r];
}

__global__ __launch_bounds__(256) void prep_kernel(
    const float* __restrict__ x, unsigned short* __restrict__ xb,
    const float* __restrict__ wq, unsigned short* __restrict__ wqT,
    const float* __restrict__ wp, unsigned short* __restrict__ wpT) {
  const int bid = blockIdx.x, tid = threadIdx.x;
  if (bid < 4096) {
    int i = (bid * 256 + tid) * 4;
    float4 v = *(const float4*)(x + i);
    ushort4 o;
    o.x = f2bf(v.x); o.y = f2bf(v.y); o.z = f2bf(v.z); o.w = f2bf(v.w);
    *(ushort4*)(xb + i) = o;
  } else if (bid < 4096 + 3072) {
    tr32(wq, wqT, 1024, 3072, bid - 4096, 96, tid);
  } else {
    tr32(wp, wpT, 1024, 1024, bid - 7168, 32, tid);
  }
}

// ---------------- GEMM1 (r0 exact — proven 528 TF, 6 blocks/CU) --------------
// FINAL model (r0-r8): per-CU LDS-DMA service ~20 B/cyc ONLY at ~6 staggered
// blocks/CU (duty-cycle); fewer blocks -> ~12 B/cyc regardless of waves/block
// (r1/r3/r8 all ~12). gemm1 47.3us = 590MB/12.2TB/s is THIS structure family's
// ceiling; 5 rewrites (r1,r2,r3,r7,r8) all regressed. Do not touch again.
// MODE 0: scatter-write q*QSCALE [B,H,T,D], k [B,H,T,D], v [B,H,D,T] bf16
// MODE 1: write fp32 out [m][n] (N=1024)
template <int MODE>
__global__ __launch_bounds__(256) void gemm_kernel(
    const unsigned short* __restrict__ A, const unsigned short* __restrict__ Bt,
    unsigned short* __restrict__ qo, unsigned short* __restrict__ ko,
    unsigned short* __restrict__ vo, float* __restrict__ fo) {
  __shared__ unsigned short As[128 * 64];   // [row][64], chunk-swizzled
  __shared__ unsigned short Bs[64 * 64];    // [row][64], chunk-swizzled
  const int tid = threadIdx.x;
  const int wave = tid >> 6, lane = tid & 63;
  const int quad = lane >> 4, l16 = lane & 15;
  const int wm = (wave >> 1) * 64, wn = (wave & 1) * 32;
  const int m0 = blockIdx.y * 128, n0 = blockIdx.x * 64;

  f32x4 acc[4][2] = {};

  for (int k = 0; k < 1024; k += 64) {
    __syncthreads();
#pragma unroll
    for (int i = 0; i < 4; i++) {
      const int s = tid + 256 * i;
      const int row = s >> 3, ch = s & 7;
      gld16(A + (size_t)(m0 + row) * 1024 + k + ((ch ^ (row & 7)) * 8), As + s * 8);
    }
#pragma unroll
    for (int i = 0; i < 2; i++) {
      const int s = tid + 256 * i;
      const int row = s >> 3, ch = s & 7;
      gld16(Bt + (size_t)(n0 + row) * 1024 + k + ((ch ^ (row & 7)) * 8), Bs + s * 8);
    }
    __syncthreads();
#pragma unroll
    for (int sub = 0; sub < 2; sub++) {
      bf16x8 af[4], bfr[2];
#pragma unroll
      for (int mi = 0; mi < 4; mi++) {
        const int row = wm + mi * 16 + l16;
        af[mi] = *(const bf16x8*)(As + row * 64 + (((sub * 4 + quad) ^ (row & 7)) * 8));
      }
#pragma unroll
      for (int ni = 0; ni < 2; ni++) {
        const int row = wn + ni * 16 + l16;
        bfr[ni] = *(const bf16x8*)(Bs + row * 64 + (((sub * 4 + quad) ^ (row & 7)) * 8));
      }
#pragma unroll
      for (int mi = 0; mi < 4; mi++)
#pragma unroll
        for (int ni = 0; ni < 2; ni++)
          acc[mi][ni] = __builtin_amdgcn_mfma_f32_16x16x32_bf16(af[mi], bfr[ni], acc[mi][ni], 0, 0, 0);
    }
  }

  // epilogue: C/D layout col=l16, row=quad*4+r (m89/m91-verified)
  if (MODE == 0) {
    const int part = n0 >> 10;          // block-uniform
    const int hh = (n0 >> 6) & 15;      // block-uniform
#pragma unroll
    for (int mi = 0; mi < 4; mi++) {
#pragma unroll
      for (int r = 0; r < 4; r++) {
        const int m = m0 + wm + mi * 16 + quad * 4 + r;
        const int b = m >> 11, t = m & 2047;
#pragma unroll
        for (int ni = 0; ni < 2; ni++) {
          const int d = wn + ni * 16 + l16;
          float val = acc[mi][ni][r];
          if (part == 0) val *= QSCALE;   // fold softmax scale into Q (fp32, free)
          const unsigned short bv = f2bf(val);
          if (part == 0)
            qo[((size_t)(b * H_ + hh) * T_ + t) * D_ + d] = bv;
          else if (part == 1)
            ko[((size_t)(b * H_ + hh) * T_ + t) * D_ + d] = bv;
          else
            vo[((size_t)(b * H_ + hh) * D_ + d) * T_ + t] = bv;  // V pre-transposed [B,H,D,T]
        }
      }
    }
  } else {
#pragma unroll
    for (int mi = 0; mi < 4; mi++)
#pragma unroll
      for (int r = 0; r < 4; r++) {
        const int m = m0 + wm + mi * 16 + quad * 4 + r;
#pragma unroll
        for (int ni = 0; ni < 2; ni++)
          fo[(size_t)m * 1024 + n0 + wn + ni * 16 + l16] = acc[mi][ni][r];
      }
  }
}

// ---------------- GEMM2: 64x64 tile, high-occupancy 2-phase (r5 exact) -------
__global__ __launch_bounds__(256) void gemm2_kernel(
    const unsigned short* __restrict__ A, const unsigned short* __restrict__ Bt,
    float* __restrict__ fo) {
  __shared__ unsigned short As[64 * 64];   // 8KB, chunk-swizzled
  __shared__ unsigned short Bs[64 * 64];   // 8KB, chunk-swizzled
  const int tid = threadIdx.x;
  const int wave = tid >> 6, lane = tid & 63;
  const int quad = lane >> 4, l16 = lane & 15;
  const int wm = (wave >> 1) * 32, wn = (wave & 1) * 32;
  const int m0 = blockIdx.y * 64, n0 = blockIdx.x * 64;

  f32x4 acc[2][2] = {};

  for (int k = 0; k < 1024; k += 64) {
    __syncthreads();
#pragma unroll
    for (int i = 0; i < 2; i++) {
      const int s = tid + 256 * i;
      const int row = s >> 3, ch = s & 7;
      gld16(A + (size_t)(m0 + row) * 1024 + k + ((ch ^ (row & 7)) * 8), As + s * 8);
      gld16(Bt + (size_t)(n0 + row) * 1024 + k + ((ch ^ (row & 7)) * 8), Bs + s * 8);
    }
    __syncthreads();
#pragma unroll
    for (int sub = 0; sub < 2; sub++) {
      bf16x8 af[2], bfr[2];
#pragma unroll
      for (int mi = 0; mi < 2; mi++) {
        const int row = wm + mi * 16 + l16;
        af[mi] = *(const bf16x8*)(As + row * 64 + (((sub * 4 + quad) ^ (row & 7)) * 8));
      }
#pragma unroll
      for (int ni = 0; ni < 2; ni++) {
        const int row = wn + ni * 16 + l16;
        bfr[ni] = *(const bf16x8*)(Bs + row * 64 + (((sub * 4 + quad) ^ (row & 7)) * 8));
      }
#pragma unroll
      for (int mi = 0; mi < 2; mi++)
#pragma unroll
        for (int ni = 0; ni < 2; ni++)
          acc[mi][ni] = __builtin_amdgcn_mfma_f32_16x16x32_bf16(af[mi], bfr[ni], acc[mi][ni], 0, 0, 0);
    }
  }

  // epilogue: C/D layout col=l16, row=quad*4+r
#pragma unroll
  for (int mi = 0; mi < 2; mi++)
#pragma unroll
    for (int r = 0; r < 4; r++) {
      const int m = m0 + wm + mi * 16 + quad * 4 + r;
#pragma unroll
      for (int ni = 0; ni < 2; ni++)
        fo[(size_t)m * 1024 + n0 + wn + ni * 16 + l16] = acc[mi][ni][r];
    }
}

// ---------------- flash attention: Q-tile 128 + staggered K/V waits (r9) ------
// r9 change vs r6: split the staging drain (T4 counted-vmcnt, m201-proven).
// Old: __syncthreads drains BOTH K and V before any compute (full V latency on
// the critical path). New: s_barrier -> issue K then V -> vmcnt(1) (own K) ->
// s_barrier -> QK^T + softmax + P-pack WHILE V is in flight -> vmcnt(0) ->
// s_barrier -> PV. Overwrite-safe: leading barrier guarantees all waves are
// past the previous round's Ks (QK) and Vt (PV) reads before new DMA lands;
// vmcnt counts are exact (each round ends fully drained).
__device__ const unsigned char CHUNK_TAB[30] = {
    // (qs<<4)|(c<<2)|nch, sorted by chunk length desc
    0x71, 0x61, 0x51, 0xF7, 0xFB, 0x41, 0x92, 0x96, 0xDB, 0xE3,
    0xE7, 0xEB, 0xF3, 0x82, 0x86, 0xC7, 0xCB, 0xD3, 0xD7, 0x31,
    0xAB, 0xB3, 0xB7, 0xBB, 0xC3, 0xA3, 0xA7, 0x21, 0x11, 0x01};

__global__ __launch_bounds__(512) void attn_kernel(
    const unsigned short* __restrict__ qb, const unsigned short* __restrict__ kb,
    const unsigned short* __restrict__ vb, unsigned short* __restrict__ yb,
    unsigned short* __restrict__ po, float* __restrict__ pl) {
  const int tid = threadIdx.x;
  const int wave = tid >> 6, lane = tid & 63;
  const int quad = lane >> 4, l16 = lane & 15;

  const int bid = blockIdx.x;
  const int bh = bid & 31;          // XCD-local: all chunks of bh on one XCD
  const int u = bid >> 5;           // 0..29, longest chunks first
  const int e = CHUNK_TAB[u];
  const int qs = e >> 4, c = (e >> 2) & 3, nch = e & 3;
  const int nt = 2 * qs + 2;
  const int j0 = c * nt / nch, j1 = (c + 1) * nt / nch;
  const int b = bh >> 4, h = bh & 15;

  __shared__ unsigned short Ks[64 * 64];     // [s][d], chunk-swizzled, 8KB
  __shared__ unsigned short Vt[64 * 64];     // [d][s], chunk-swizzled, 8KB
  __shared__ unsigned short Ps[8 * 16 * 68]; // per-wave P [q][s], stride 68
  unsigned short* Pw = Ps + wave * 16 * 68;

  const unsigned short* Qg = qb + (size_t)bh * T_ * D_;
  const unsigned short* Kg = kb + (size_t)bh * T_ * D_;
  const unsigned short* Vg = vb + (size_t)bh * D_ * T_;

  // Q fragment (B-operand: n=q=l16, k=d=quad*8+j); wave owns 16 q-rows
  const int qrow0 = qs * 128 + wave * 16;
  const unsigned short* qp = Qg + (size_t)(qrow0 + l16) * D_ + quad * 8;
  bf16x8 qf0 = *(const bf16x8*)qp, qf1 = *(const bf16x8*)(qp + 32);

  f32x4 o[4] = {};
  float lacc = 0.f;
  const int qglob = qrow0 + l16;                 // this lane's q (S^T: col=l16)
  const int sloc_base = quad * 4;                // s-local row base (S^T: row=quad*4+r)
  const int diag0 = 2 * qs;                      // first tile needing masking

  const int trow = tid >> 3, tch = tid & 7;      // 512 thr: rows 0..63, ch 0..7

  for (int jt = j0; jt < j1; jt++) {
    const int s0 = jt * 64;
    __builtin_amdgcn_s_barrier();   // all waves past prev round's Ks/Vt reads
    // issue K first, then V (per-wave order -> vmcnt(1) == K landed)
    gld16(Kg + (size_t)(s0 + trow) * D_ + ((tch ^ (trow & 7)) * 8), Ks + trow * 64 + tch * 8);
    gld16(Vg + (size_t)trow * T_ + s0 + ((tch ^ (trow & 7)) * 8), Vt + trow * 64 + tch * 8);
    asm volatile("s_waitcnt vmcnt(1)" ::: "memory");   // own K landed (V in flight)
    __builtin_amdgcn_s_barrier();                      // all K visible
    __builtin_amdgcn_sched_barrier(0);

    // S^T = K Q^T : K as A-operand, Q as B-operand.
    // C-layout of s[mi]: row = s-local = mi*16+quad*4+r, col = q = l16.
    f32x4 s[4];
#pragma unroll
    for (int mi = 0; mi < 4; mi++) {
      const int row = mi * 16 + l16, sw = row & 7;
      bf16x8 kf0 = *(const bf16x8*)(Ks + row * 64 + ((quad ^ sw) * 8));
      bf16x8 kf1 = *(const bf16x8*)(Ks + row * 64 + (((quad + 4) ^ sw) * 8));
      f32x4 z = {0.f, 0.f, 0.f, 0.f};
      z = __builtin_amdgcn_mfma_f32_16x16x32_bf16(kf0, qf0, z, 0, 0, 0);
      s[mi] = __builtin_amdgcn_mfma_f32_16x16x32_bf16(kf1, qf1, z, 0, 0, 0);
    }

    if (jt >= diag0) {  // uniform diag branch: mask s > q (both diagonal tiles)
#pragma unroll
      for (int mi = 0; mi < 4; mi++)
#pragma unroll
        for (int r = 0; r < 4; r++) {
          float p = EXP2(s[mi][r]);
          p = (s0 + mi * 16 + sloc_base + r > qglob) ? 0.f : p;
          s[mi][r] = p;
          lacc += p;
        }
    } else {
#pragma unroll
      for (int mi = 0; mi < 4; mi++)
#pragma unroll
        for (int r = 0; r < 4; r++) {
          float p = EXP2(s[mi][r]);
          s[mi][r] = p;
          lacc += p;
        }
    }

    // P -> LDS [q=l16][s], packed dwords
#pragma unroll
    for (int mi = 0; mi < 4; mi++) {
      unsigned d0 = pack_bf2(s[mi][0], s[mi][1]);
      unsigned d1 = pack_bf2(s[mi][2], s[mi][3]);
      *(uint2*)(Pw + l16 * 68 + mi * 16 + quad * 4) = make_uint2(d0, d1);
    }

    asm volatile("s_waitcnt vmcnt(0)" ::: "memory");   // own V landed
    __builtin_amdgcn_s_barrier();                      // all V visible
    __builtin_amdgcn_sched_barrier(0);

    // O += P V : P as A-operand (m=q=l16, k=s), V^T as B-operand
#pragma unroll
    for (int kk = 0; kk < 2; kk++) {
      bf16x8 pf = *(const bf16x8*)(Pw + l16 * 68 + kk * 32 + quad * 8);
#pragma unroll
      for (int ni = 0; ni < 4; ni++) {
        const int row = ni * 16 + l16, sw = row & 7;
        bf16x8 vf = *(const bf16x8*)(Vt + row * 64 + (((kk * 4 + quad) ^ sw) * 8));
        o[ni] = __builtin_amdgcn_mfma_f32_16x16x32_bf16(pf, vf, o[ni], 0, 0, 0);
      }
    }
  }

  // l: sum across the 4 lanes sharing l16 (quads), then fetch per-row values
  lacc += __shfl_xor(lacc, 16, 64);
  lacc += __shfl_xor(lacc, 32, 64);
  float lr[4];
#pragma unroll
  for (int r = 0; r < 4; r++) lr[r] = __shfl(lacc, quad * 4 + r, 16);  // l for q-row quad*4+r

  if (nch == 1) {
#pragma unroll
    for (int r = 0; r < 4; r++) {
      float inv = 1.0f / lr[r];
      int tq = qrow0 + quad * 4 + r;
#pragma unroll
      for (int ni = 0; ni < 4; ni++)
        yb[((size_t)(b * T_ + tq)) * 1024 + h * 64 + ni * 16 + l16] = f2bf(o[ni][r] * inv);
    }
  } else {
    // split slots: qs 8,9 -> (qs-8)*2 + c; qs 10..15 -> 4 + (qs-10)*3 + c
    const int slot = 22 * bh + ((qs < 10) ? ((qs - 8) * 2 + c) : (4 + (qs - 10) * 3 + c));
    unsigned short* pob = po + (size_t)slot * 8192;
#pragma unroll
    for (int r = 0; r < 4; r++) {
      const int row128 = wave * 16 + quad * 4 + r;
#pragma unroll
      for (int ni = 0; ni < 4; ni++)
        pob[row128 * 64 + ni * 16 + l16] = f2bf(o[ni][r]);
      if (l16 == 0) pl[slot * 128 + row128] = lr[r];
    }
  }
}

// ---------------- split-K reduce: q-blocks qs>=8 (128 rows each) --------------
__global__ __launch_bounds__(256) void reduce_kernel(
    const unsigned short* __restrict__ po, const float* __restrict__ pl,
    unsigned short* __restrict__ yb) {
  int idx = blockIdx.x * 256 + threadIdx.x;   // 32 bh * 8 qsplit * 128 rows * 16 cg
  int bh = idx >> 14;
  int rem = idx & 16383;
  int qs = 8 + (rem >> 11);
  int row128 = (rem >> 4) & 127;
  int cg = rem & 15;
  int base, nch;
  if (qs < 10) { base = (qs - 8) * 2; nch = 2; }
  else { base = 4 + (qs - 10) * 3; nch = 3; }
  int b = bh >> 4, h = bh & 15;
  float a0 = 0.f, a1 = 0.f, a2 = 0.f, a3 = 0.f, l = 0.f;
  for (int cc = 0; cc < nch; cc++) {
    int slot = 22 * bh + base + cc;
    const unsigned short* p = po + (size_t)slot * 8192 + row128 * 64 + cg * 4;
    ushort4 uv = *(const ushort4*)p;
    a0 += bf2f(uv.x); a1 += bf2f(uv.y); a2 += bf2f(uv.z); a3 += bf2f(uv.w);
    l += pl[slot * 128 + row128];
  }
  float inv = 1.0f / l;
  int tq = qs * 128 + row128;
  ushort4 w;
  w.x = f2bf(a0 * inv); w.y = f2bf(a1 * inv); w.z = f2bf(a2 * inv); w.w = f2bf(a3 * inv);
  *(ushort4*)(yb + ((size_t)(b * T_ + tq)) * 1024 + h * 64 + cg * 4) = w;
}

// ---------------- launch ----------------
extern "C" void kernel_launch(void* const* d_in, const int* in_sizes, int n_in,
                              void* d_out, int out_size, void* d_ws, size_t ws_size,
                              hipStream_t stream) {
  const float* x = (const float*)d_in[0];       // [B,T,C]
  const float* w_qkv = (const float*)d_in[1];   // [C,3C]
  const float* w_proj = (const float*)d_in[2];  // [C,C]
  float* out = (float*)d_out;                   // [B,T,C] fp32

  // ws layout (shorts). po aliases wqkvT (dead after GEMM1). ~47.6 MB total.
  unsigned short* xb = (unsigned short*)d_ws;                 // 4.19M shorts
  unsigned short* wprojT = xb + (size_t)BT_ * C_;             // 1.05M
  unsigned short* qb = wprojT + (size_t)C_ * C_;              // 4.19M
  unsigned short* kb = qb + (size_t)B_ * H_ * T_ * D_;        // 4.19M
  unsigned short* vb = kb + (size_t)B_ * H_ * T_ * D_;        // 4.19M
  unsigned short* wqkvT = vb + (size_t)B_ * H_ * T_ * D_;     // 3.15M
  unsigned short* po = wqkvT;                                 // 704 slots * 8192 = 5.77M
  float* pl = (float*)(po + (size_t)704 * 8192);              // 90K fp32
  unsigned short* yb = xb;  // reuse (x dead after GEMM1)

  prep_kernel<<<dim3(8192), 256, 0, stream>>>(x, xb, w_qkv, wqkvT, w_proj, wprojT);

  gemm_kernel<0><<<dim3(N3_ / 64, BT_ / 128), 256, 0, stream>>>(xb, wqkvT, qb, kb, vb, nullptr);
  attn_kernel<<<dim3(32 * 30), 512, 0, stream>>>(qb, kb, vb, yb, po, pl);
  reduce_kernel<<<dim3(2048), 256, 0, stream>>>(po, pl, yb);
  gemm2_kernel<<<dim3(C_ / 64, BT_ / 64), 256, 0, stream>>>(yb, wprojT, out);
}